// Round 9
// baseline (848.822 us; speedup 1.0000x reference)
//
#include <hip/hip_runtime.h>
#include <hip/hip_bf16.h>

#define B_ 32
#define N_ 512
#define NB_ 10
#define E_ 1024
#define H_ 256
#define A_ 82
#define K_ 4
#define D_ 3
#define M_ (B_*N_)   // 16384 rows

typedef unsigned short u16;
typedef __attribute__((ext_vector_type(8))) short bf16x8;
typedef __attribute__((ext_vector_type(4))) float f32x4;

__device__ __forceinline__ float b2f(u16 u){
    unsigned int x = ((unsigned int)u) << 16;
    return __builtin_bit_cast(float, x);
}
__device__ __forceinline__ u16 f2b(float f){
    unsigned int x = __builtin_bit_cast(unsigned int, f);
    unsigned int lsb = (x >> 16) & 1u;
    x += 0x7fffu + lsb;
    return (u16)(x >> 16);
}
__device__ __forceinline__ float sigmoidf_(float x){ return 1.f/(1.f+expf(-x)); }

// ---- conversion table: 31 float tensors (atom excluded; ints excluded) ----
static constexpr int CVT_N[31] = {
    B_*E_*6, B_*N_*NB_, B_*N_,
    A_*H_, H_,
    D_*K_*H_*H_, D_*K_*H_, D_*K_*H_*H_, D_*K_*H_,
    D_*K_*H_*H_, D_*K_*H_, D_*K_*H_, D_*K_,
    D_*K_*H_*H_, D_*H_, D_*H_*H_, D_*H_,
    D_*H_*H_, D_*H_, D_*H_*H_, D_*H_,
    D_*H_*H_, D_*H_, D_*H_*H_, D_*H_,
    D_*H_*H_, D_*H_, D_*(H_+6)*H_, D_*H_,
    D_*2*H_*H_, D_*H_
};
struct Offs { long v[32]; };
static constexpr Offs mk_offs(){
    Offs o{}; o.v[0]=0;
    for(int i=0;i<31;i++) o.v[i+1]=o.v[i]+CVT_N[i];
    return o;
}
static constexpr Offs CVT_OFF = mk_offs();

struct Ptrs { const void* p[31]; };

// ---------------- dtype detection: bf16 vs f32 ----------------
__global__ void k_detect(const unsigned short* __restrict__ wv_raw, int* __restrict__ flag){
    float v = b2f(wv_raw[threadIdx.x]);
    bool plaus = (v==v) && (fabsf(v) < 100.0f);
    unsigned long long m = __ballot(plaus);
    if (threadIdx.x==0) *flag = (m == ~0ULL) ? 1 : 0;
}

// ---------------- convert float inputs to fp32 workspace ----------------
__global__ void k_cvt(Ptrs ptrs, float* __restrict__ dst, const int* __restrict__ flag){
    int t = blockIdx.y;
    int n = CVT_N[t];
    int i4 = blockIdx.x*256 + threadIdx.x;
    if (i4*4 >= n) return;
    const void* src = ptrs.p[t];
    float4 o;
    if (*flag){
        ushort4 u = ((const ushort4*)src)[i4];
        o.x=b2f(u.x); o.y=b2f(u.y); o.z=b2f(u.z); o.w=b2f(u.w);
    } else {
        o = ((const float4*)src)[i4];
    }
    *(float4*)(dst + CVT_OFF.v[t] + (size_t)i4*4) = o;
}

// ======== WT precompute: 24 H×H matrices -> bf16, tiled [mi][k0/32][n][32] ========
__global__ void k_wt(const float* __restrict__ Wam, const float* __restrict__ Wu2,
                     const float* __restrict__ Wu1, const float* __restrict__ Wzm1,
                     u16* __restrict__ WT){
    int mi = blockIdx.z;
    const float* src;
    if (mi<12)      src = Wam  + (size_t)mi*H_*H_;
    else if (mi<15) src = Wu2  + (size_t)(mi-12)*(H_+6)*H_;
    else if (mi<18) src = Wu1  + (size_t)(mi-15)*2*H_*H_;
    else if (mi<21) src = Wu1  + (size_t)(mi-18)*2*H_*H_ + (size_t)H_*H_;
    else            src = Wzm1 + (size_t)(mi-21)*H_*H_;
    __shared__ float t[32][33];
    int x = threadIdx.x, y = threadIdx.y;
    int k0 = blockIdx.y*32, n0 = blockIdx.x*32;
    for(int yy=y; yy<32; yy+=8) t[yy][x] = src[(size_t)(k0+yy)*H_ + n0+x];
    __syncthreads();
    u16* dst = WT + ((size_t)mi*8 + (k0>>5))*(256*32);
    for(int yy=y; yy<32; yy+=8) dst[(size_t)(n0+yy)*32 + x] = f2b(t[x][yy]);
}

// ---------------- vertex embedding: 8 rows per block, bf16 out ----------------
__global__ void k_embed(const u16* __restrict__ atom, const float* __restrict__ Wv,
                        const float* __restrict__ bv, u16* __restrict__ vfb,
                        const int* __restrict__ flag){
    __shared__ float arow[8][A_];
    int r0 = blockIdx.x*8; int j = threadIdx.x;
    int fl = *flag;
    for(int i=j;i<8*A_;i+=256){
        int r=i/A_, a=i-r*A_;
        arow[r][a] = fl ? b2f(atom[(size_t)(r0+r)*A_+a])
                        : ((const float*)atom)[(size_t)(r0+r)*A_+a];
    }
    __syncthreads();
    float acc[8];
    float bj = bv[j];
    #pragma unroll
    for(int r=0;r<8;r++) acc[r]=bj;
    for(int a=0;a<A_;a++){
        float w = Wv[a*H_+j];
        #pragma unroll
        for(int r=0;r<8;r++) acc[r] += arow[r][a]*w;
    }
    #pragma unroll
    for(int r=0;r<8;r++){
        float v = acc[r];
        vfb[(size_t)(r0+r)*H_+j] = f2b(v>0.f ? v : 0.01f*v);
    }
}

// ---------------- sf0 ----------------
__global__ void k_sf0(const u16* __restrict__ vfb, const float* __restrict__ dmask,
                      float* __restrict__ sf){
    int b = blockIdx.x, h = threadIdx.x;
    __shared__ float mk[N_];
    for(int n=threadIdx.x;n<N_;n+=256) mk[n] = dmask[b*N_+n];
    __syncthreads();
    float s=0.f;
    #pragma unroll 8
    for(int n=0;n<N_;n++) s += mk[n]*b2f(vfb[((size_t)b*N_+n)*H_ + h]);
    sf[b*H_+h]=s;
}

// ======== S1: batched GEMV from sf: asw(k=0..3), s2m(m=4), ssf(m=5) ========
__global__ void k_s1(int d, const float* __restrict__ sf,
    const float* __restrict__ Was, const float* __restrict__ bas,
    const float* __restrict__ Wbmm,
    const float* __restrict__ Ws2m, const float* __restrict__ bs2m,
    const float* __restrict__ Wsup, const float* __restrict__ bsup,
    float* __restrict__ asw, float* __restrict__ s2m, float* __restrict__ ssf)
{
    int b = blockIdx.x, m = blockIdx.y, j = threadIdx.x;
    __shared__ float sfl[H_];
    sfl[j] = sf[b*H_+j];
    __syncthreads();
    const float* W; float bias;
    if (m < 4){ W = Was + (size_t)(d*K_+m)*H_*H_; bias = bas[(d*K_+m)*H_+j]; }
    else if (m==4){ W = Ws2m + (size_t)d*H_*H_; bias = bs2m[d*H_+j]; }
    else { W = Wsup + (size_t)d*H_*H_; bias = bsup[d*H_+j]; }
    float acc = bias;
    #pragma unroll 8
    for(int h=0;h<H_;h++) acc += sfl[h]*W[h*H_+j];
    float v = tanhf(acc);
    if (m < 4) asw[(b*K_+m)*H_+j] = v * Wbmm[(d*K_+m)*H_+j];
    else if (m==4) s2m[b*H_+j] = v;
    else ssf[b*H_+j] = v;
}

// ======== S2: stm2 partials (h-split by 4): stm2p[c][b][j] ========
__global__ void k_s2(int d, const float* __restrict__ s2m,
    const float* __restrict__ Wzm2, const float* __restrict__ bzm2,
    float* __restrict__ stm2p)
{
    int b=blockIdx.x, c=blockIdx.y, j=threadIdx.x;
    __shared__ float xl[64];
    if (j<64) xl[j] = s2m[b*H_ + c*64 + j];
    __syncthreads();
    const float* W = Wzm2 + (size_t)d*H_*H_ + (size_t)(c*64)*H_;
    float acc = (c==0) ? bzm2[d*H_+j] : 0.f;
    #pragma unroll 8
    for(int h=0;h<64;h++) acc += xl[h]*W[h*H_+j];
    stm2p[((size_t)c*B_+b)*H_+j] = acc;
}

// ================= MFMA core v2: A preloaded to LDS once; B direct from WT =================
// Als stride 264 u16 (132 dwords -> only 2-way bank aliasing, free). No barrier in k-loop.
#define LSA_ 264
__device__ __forceinline__ void mfma_core_v2(const u16* __restrict__ A,
    const u16* __restrict__ WTg, f32x4 acc[2][8], u16* __restrict__ Als)
{
    int tid = threadIdx.x;
    int lane = tid & 63, wave = tid >> 6;
    int wy = wave >> 1, wx = wave & 1;
    int quad = lane >> 4, l15 = lane & 15;
    #pragma unroll
    for(int mt=0;mt<2;mt++)
        #pragma unroll
        for(int nt=0;nt<8;nt++) acc[mt][nt] = (f32x4){0.f,0.f,0.f,0.f};
    int arow = tid >> 2;
    int ac   = (tid & 3) * 8;
    #pragma unroll
    for(int c=0;c<8;c++)
        *(bf16x8*)(Als + arow*LSA_ + ac + c*32) =
            *(const bf16x8*)(A + (size_t)arow*H_ + ac + c*32);
    __syncthreads();
    #pragma unroll
    for(int k0=0;k0<H_;k0+=32){
        bf16x8 af[2], bfr[8];
        #pragma unroll
        for(int mt=0;mt<2;mt++)
            af[mt] = *(const bf16x8*)(Als + (wy*32+mt*16+l15)*LSA_ + k0 + quad*8);
        const u16* wsrc = WTg + (size_t)(k0>>5)*(256*32);
        #pragma unroll
        for(int nt=0;nt<8;nt++)
            bfr[nt] = *(const bf16x8*)(wsrc + (wx*128+nt*16+l15)*32 + quad*8);
        #pragma unroll
        for(int mt=0;mt<2;mt++)
            #pragma unroll
            for(int nt=0;nt<8;nt++)
                acc[mt][nt] = __builtin_amdgcn_mfma_f32_16x16x32_bf16(
                    af[mt], bfr[nt], acc[mt][nt], 0,0,0);
    }
}

// ================= big GEMM over vfb =================
__global__ __launch_bounds__(256) void k_gemm_big(int d, const u16* __restrict__ vfb,
    const u16* __restrict__ WT, const float* __restrict__ ba_main,
    const float* __restrict__ bbmm, const float* __restrict__ bu1,
    const float* __restrict__ asw, float* __restrict__ score,
    u16* __restrict__ projb, float* __restrict__ pu1a)
{
    __shared__ u16 Als[64*LSA_];
    __shared__ float sred[64][33];
    int m0 = blockIdx.x*64;
    int seg = blockIdx.y;
    int b = m0 >> 9;
    int mi;
    if (seg < 4)      mi = d*4+seg;
    else if (seg==4)  mi = 12+d;
    else              mi = 15+d;
    f32x4 acc[2][8];
    mfma_core_v2(vfb + (size_t)m0*H_, WT + (size_t)mi*H_*H_, acc, Als);
    int tid=threadIdx.x, lane=tid&63, wave=tid>>6;
    int wy=wave>>1, wx=wave&1, quad=lane>>4, l15=lane&15;
    if (seg < 4){
        const float* aswp = asw + (size_t)(b*K_+seg)*H_;
        const float* bap  = ba_main + (size_t)(d*K_+seg)*H_;
        float bbv[8], awv[8];
        #pragma unroll
        for(int nt=0;nt<8;nt++){
            int col = wx*128+nt*16+l15;
            bbv[nt]=bap[col]; awv[nt]=aswp[col];
        }
        #pragma unroll
        for(int mt=0;mt<2;mt++)
            #pragma unroll
            for(int r=0;r<4;r++){
                float p=0.f;
                #pragma unroll
                for(int nt=0;nt<8;nt++)
                    p += tanhf(acc[mt][nt][r]+bbv[nt])*awv[nt];
                int row = wy*32+mt*16+quad*4+r;
                sred[row][wx*16+l15] = p;
            }
        __syncthreads();
        if (tid < 64){
            float s=0.f;
            #pragma unroll 8
            for(int i=0;i<32;i++) s += sred[tid][i];
            score[(size_t)(b*K_+seg)*N_ + (m0&511) + tid] = s + bbmm[d*K_+seg];
        }
    } else if (seg==4){
        #pragma unroll
        for(int mt=0;mt<2;mt++)
            #pragma unroll
            for(int nt=0;nt<8;nt++){
                int col = wx*128+nt*16+l15;
                #pragma unroll
                for(int r=0;r<4;r++){
                    int row = m0 + wy*32+mt*16+quad*4+r;
                    projb[(size_t)row*H_+col] = f2b(acc[mt][nt][r]);
                }
            }
    } else {
        const float* bp = bu1 + d*H_;
        #pragma unroll
        for(int mt=0;mt<2;mt++)
            #pragma unroll
            for(int nt=0;nt<8;nt++){
                int col = wx*128+nt*16+l15;
                float bb = bp[col];
                #pragma unroll
                for(int r=0;r<4;r++){
                    int row = m0 + wy*32+mt*16+quad*4+r;
                    pu1a[(size_t)row*H_+col] = acc[mt][nt][r] + bb;
                }
            }
    }
}

// ===== main_self = lrelu(neib @ Wu1[H:] + pu1a, 0.1) -> msb (bf16) =====
__global__ __launch_bounds__(256) void k_mainself(int d, const u16* __restrict__ neib,
    const u16* __restrict__ WT, const float* __restrict__ pu1a, u16* __restrict__ msb)
{
    __shared__ u16 Als[64*LSA_];
    int m0 = blockIdx.x*64;
    f32x4 acc[2][8];
    mfma_core_v2(neib + (size_t)m0*H_, WT + (size_t)(18+d)*H_*H_, acc, Als);
    int tid=threadIdx.x, lane=tid&63, wave=tid>>6;
    int wy=wave>>1, wx=wave&1, quad=lane>>4, l15=lane&15;
    #pragma unroll
    for(int mt=0;mt<2;mt++)
        #pragma unroll
        for(int nt=0;nt<8;nt++){
            int col = wx*128+nt*16+l15;
            #pragma unroll
            for(int r=0;r<4;r++){
                int row = m0 + wy*32+mt*16+quad*4+r;
                float v = acc[mt][nt][r] + pu1a[(size_t)row*H_+col];
                v = v>0.f? v : 0.1f*v;
                msb[(size_t)row*H_+col] = f2b(v);
            }
        }
}

// ===== z_main GEMM + GRU vf update =====
__global__ __launch_bounds__(256) void k_update(int d, const u16* __restrict__ msb,
    const u16* __restrict__ WT, const float* __restrict__ bzm1,
    const float* __restrict__ stm2p, const float* __restrict__ s2m, u16* __restrict__ vfb)
{
    __shared__ u16 Als[64*LSA_];
    int m0 = blockIdx.x*64; int b = m0>>9;
    f32x4 acc[2][8];
    mfma_core_v2(msb + (size_t)m0*H_, WT + (size_t)(21+d)*H_*H_, acc, Als);
    int tid=threadIdx.x, lane=tid&63, wave=tid>>6;
    int wy=wave>>1, wx=wave&1, quad=lane>>4, l15=lane&15;
    #pragma unroll
    for(int mt=0;mt<2;mt++)
        #pragma unroll
        for(int nt=0;nt<8;nt++){
            int col = wx*128+nt*16+l15;
            float bz = bzm1[d*H_+col];
            float st = stm2p[(size_t)(0*B_+b)*H_+col] + stm2p[(size_t)(1*B_+b)*H_+col]
                     + stm2p[(size_t)(2*B_+b)*H_+col] + stm2p[(size_t)(3*B_+b)*H_+col];
            float sm = s2m[b*H_+col];
            #pragma unroll
            for(int r=0;r<4;r++){
                int row = m0 + wy*32+mt*16+quad*4+r;
                float z = sigmoidf_(acc[mt][nt][r] + bz + st);
                float ms = b2f(msb[(size_t)row*H_+col]);
                vfb[(size_t)row*H_+col] = f2b((1.f-z)*ms + z*sm);
            }
        }
}

// ======== fused masked softmax + t = attn @ vf ========
__global__ void k_attn(const float* __restrict__ score, const float* __restrict__ dmask,
                       const u16* __restrict__ vfb, float* __restrict__ tbuf,
                       float* __restrict__ sumattn){
    int b = blockIdx.x, k = blockIdx.y;
    int tid = threadIdx.x;
    __shared__ float sh[256];
    __shared__ float at[N_];
    const float* a = score + (size_t)(b*K_+k)*N_;
    float v0 = a[tid], v1 = a[tid+256];
    sh[tid]=fmaxf(v0,v1); __syncthreads();
    for(int s=128;s>0;s>>=1){ if(tid<s) sh[tid]=fmaxf(sh[tid],sh[tid+s]); __syncthreads(); }
    float m = sh[0]; __syncthreads();
    float e0 = expf(v0-m)*dmask[b*N_+tid], e1 = expf(v1-m)*dmask[b*N_+tid+256];
    sh[tid]=e0+e1; __syncthreads();
    for(int s=128;s>0;s>>=1){ if(tid<s) sh[tid]+=sh[tid+s]; __syncthreads(); }
    float S = sh[0];
    float inv = 1.f/(S+1e-6f);
    at[tid]=e0*inv; at[tid+256]=e1*inv;
    if(tid==0) sumattn[b*K_+k]=S*inv;
    __syncthreads();
    // t[h] = sum_n at[n] * vf[b,n,h]
    float acc=0.f;
    const u16* vfp = vfb + (size_t)b*N_*H_ + tid;
    #pragma unroll 8
    for(int n=0;n<N_;n++) acc += at[n]*b2f(vfp[(size_t)n*H_]);
    tbuf[(size_t)(b*K_+k)*H_+tid]=acc;
}

// ======== fused M1+M2: m2s in LDS -> mtsp[k][b][j] ========
__global__ void k_m12(int d, const float* __restrict__ tbuf, const float* __restrict__ sumattn,
    const float* __restrict__ Wm, const float* __restrict__ bm,
    const float* __restrict__ Wm2s, float* __restrict__ mtsp)
{
    int b=blockIdx.x, k=blockIdx.y, j=threadIdx.x;
    __shared__ float tl[H_];
    __shared__ float m2sl[H_];
    tl[j] = tbuf[(size_t)(b*K_+k)*H_+j];
    __syncthreads();
    {
        const float* W = Wm + (size_t)(d*K_+k)*H_*H_;
        float acc = sumattn[b*K_+k]*bm[(d*K_+k)*H_+j];
        #pragma unroll 8
        for(int h=0;h<H_;h++) acc += tl[h]*W[h*H_+j];
        m2sl[j]=acc;
    }
    __syncthreads();
    {
        const float* W = Wm2s + (size_t)d*(K_*H_)*H_ + (size_t)(k*H_)*H_;
        float acc=0.f;
        #pragma unroll 8
        for(int h=0;h<H_;h++) acc += m2sl[h]*W[h*H_+j];
        mtsp[((size_t)k*B_+b)*H_+j]=acc;
    }
}

// ======== fused tail: mts -> p1,p2 -> sf GRU update ========
__global__ void k_sftail(int d, const float* __restrict__ mtsp, const float* __restrict__ bm2s,
    const float* __restrict__ ssf,
    const float* __restrict__ Wzs1, const float* __restrict__ bzs1,
    const float* __restrict__ Wzs2, const float* __restrict__ bzs2,
    float* __restrict__ sf)
{
    int b=blockIdx.x, j=threadIdx.x;
    __shared__ float mtsl[H_];
    __shared__ float ssl[H_];
    {
        float acc = bm2s[d*H_+j];
        #pragma unroll
        for(int c=0;c<4;c++) acc += mtsp[((size_t)c*B_+b)*H_+j];
        mtsl[j]=tanhf(acc);
        ssl[j]=ssf[b*H_+j];
    }
    __syncthreads();
    const float* W1 = Wzs1 + (size_t)d*H_*H_;
    const float* W2 = Wzs2 + (size_t)d*H_*H_;
    float acc = bzs1[d*H_+j] + bzs2[d*H_+j];
    #pragma unroll 4
    for(int h=0;h<H_;h++) acc += ssl[h]*W1[h*H_+j] + mtsl[h]*W2[h*H_+j];
    float z = sigmoidf_(acc);
    sf[b*H_+j]=(1.f-z)*ssl[j]+z*mtsl[j];
}

// ---- nei = sum_j mask * lrelu(projb[anb] + bond@Wu2[H:] + bu2, 0.1) -> bf16 ----
__global__ void k_nei(int d, const int* __restrict__ anb, const int* __restrict__ bnb,
    const float* __restrict__ nbm, const float* __restrict__ bond,
    const float* __restrict__ Wu2, const float* __restrict__ bu2,
    const u16* __restrict__ projb, u16* __restrict__ neib)
{
    __shared__ float W2s[6][256];
    __shared__ float bfeat[NB_][6];
    __shared__ int ai[NB_]; __shared__ int bi[NB_]; __shared__ float mk[NB_];
    int row = blockIdx.x; int b = row >> 9; int h = threadIdx.x;
    const float* W2 = Wu2 + (size_t)d*(H_+6)*H_ + (size_t)H_*H_;
    for(int i=h;i<6*H_;i+=256) W2s[i>>8][i&255] = W2[i];
    if (h<NB_){ ai[h]=anb[row*NB_+h]; bi[h]=bnb[row*NB_+h]; mk[h]=nbm[row*NB_+h]; }
    __syncthreads();
    if (h<NB_*6){ int jn=h/6, i=h-jn*6; bfeat[jn][i]=bond[((size_t)b*E_+bi[jn])*6+i]; }
    __syncthreads();
    float bu = bu2[d*H_+h];
    float acc=0.f;
    #pragma unroll
    for(int jn=0;jn<NB_;jn++){
        float v = b2f(projb[((size_t)b*N_+ai[jn])*H_+h]) + bu;
        #pragma unroll
        for(int i=0;i<6;i++) v += bfeat[jn][i]*W2s[i][h];
        v = v>0.f? v : 0.1f*v;
        acc += mk[jn]*v;
    }
    neib[(size_t)row*H_+h]=f2b(acc);
}

// ---------------- final output ----------------
__global__ void k_out(const u16* __restrict__ vfb, const float* __restrict__ sf,
                      void* __restrict__ out, const int* __restrict__ flag){
    int idx = blockIdx.x*256 + threadIdx.x;
    const int total = M_*H_ + B_*H_;
    if (idx >= total) return;
    if (*flag){
        ((u16*)out)[idx] = (idx < M_*H_) ? vfb[idx] : f2b(sf[idx - M_*H_]);
    } else {
        ((float*)out)[idx] = (idx < M_*H_) ? b2f(vfb[idx]) : sf[idx - M_*H_];
    }
}

extern "C" void kernel_launch(void* const* d_in, const int* in_sizes, int n_in,
                              void* d_out, int out_size, void* d_ws, size_t ws_size,
                              hipStream_t stream)
{
    const int* anb = (const int*)d_in[2];
    const int* bnb = (const int*)d_in[3];

    float* ws   = (float*)d_ws;
    int*   flag = (int*)ws;                 // 256 B reserved
    float* cvt  = ws + 64;
    float* p    = cvt + ((CVT_OFF.v[31] + 63) & ~63L);
    float* pu1a      = p; p += (size_t)M_*H_;
    float* sf        = p; p += B_*H_;
    float* score     = p; p += B_*K_*N_;
    float* sumattn   = p; p += 128;
    float* asw       = p; p += B_*K_*H_;
    float* s2m       = p; p += B_*H_;
    float* ssf       = p; p += B_*H_;
    float* stm2p     = p; p += 4*B_*H_;
    float* tbuf      = p; p += B_*K_*H_;
    float* mtsp      = p; p += 4*B_*H_;
    u16*   WT        = (u16*)p;                 // 24*H*H bf16 = 3.1 MB
    u16*   vfb       = WT  + (size_t)24*H_*H_;
    u16*   projb     = vfb + (size_t)M_*H_;
    u16*   neib      = projb + (size_t)M_*H_;
    u16*   msb       = neib  + (size_t)M_*H_;

    const float* cBond = cvt + CVT_OFF.v[0];
    const float* cNbm  = cvt + CVT_OFF.v[1];
    const float* cDm   = cvt + CVT_OFF.v[2];
    const float* cWv   = cvt + CVT_OFF.v[3];
    const float* cbv   = cvt + CVT_OFF.v[4];
    const float* cWam  = cvt + CVT_OFF.v[5];
    const float* cbam  = cvt + CVT_OFF.v[6];
    const float* cWas  = cvt + CVT_OFF.v[7];
    const float* cbas  = cvt + CVT_OFF.v[8];
    const float* cWm   = cvt + CVT_OFF.v[9];
    const float* cbm   = cvt + CVT_OFF.v[10];
    const float* cWbmm = cvt + CVT_OFF.v[11];
    const float* cbbmm = cvt + CVT_OFF.v[12];
    const float* cWm2s = cvt + CVT_OFF.v[13];
    const float* cbm2s = cvt + CVT_OFF.v[14];
    const float* cWs2m = cvt + CVT_OFF.v[15];
    const float* cbs2m = cvt + CVT_OFF.v[16];
    const float* cWsup = cvt + CVT_OFF.v[17];
    const float* cbsup = cvt + CVT_OFF.v[18];
    const float* cWzm1 = cvt + CVT_OFF.v[19];
    const float* cbzm1 = cvt + CVT_OFF.v[20];
    const float* cWzm2 = cvt + CVT_OFF.v[21];
    const float* cbzm2 = cvt + CVT_OFF.v[22];
    const float* cWzs1 = cvt + CVT_OFF.v[23];
    const float* cbzs1 = cvt + CVT_OFF.v[24];
    const float* cWzs2 = cvt + CVT_OFF.v[25];
    const float* cbzs2 = cvt + CVT_OFF.v[26];
    const float* cWu2  = cvt + CVT_OFF.v[27];
    const float* cbu2  = cvt + CVT_OFF.v[28];
    const float* cWu1  = cvt + CVT_OFF.v[29];
    const float* cbu1  = cvt + CVT_OFF.v[30];

    Ptrs ptrs;
    {
        int idx[31] = {1,4,5,6,7,8,9,10,11,12,13,14,15,16,17,18,19,20,21,
                       22,23,24,25,26,27,28,29,30,31,32,33};
        for(int i=0;i<31;i++) ptrs.p[i] = d_in[idx[i]];
    }

    k_detect<<<1,64,0,stream>>>((const unsigned short*)d_in[6], flag);
    {
        int maxv4 = (D_*K_*H_*H_ + 3)/4;
        int gx = (maxv4 + 255)/256;
        k_cvt<<<dim3(gx,31),256,0,stream>>>(ptrs, cvt, flag);
    }
    k_wt<<<dim3(8,8,24),dim3(32,8),0,stream>>>(cWam, cWu2, cWu1, cWzm1, WT);

    k_embed<<<M_/8,256,0,stream>>>((const u16*)d_in[0], cWv, cbv, vfb, flag);
    k_sf0<<<B_,256,0,stream>>>(vfb, cDm, sf);
    for(int d=0; d<D_; d++){
        k_s1<<<dim3(B_,6),256,0,stream>>>(d, sf, cWas, cbas, cWbmm,
                                          cWs2m, cbs2m, cWsup, cbsup, asw, s2m, ssf);
        k_s2<<<dim3(B_,4),256,0,stream>>>(d, s2m, cWzm2, cbzm2, stm2p);
        k_gemm_big<<<dim3(M_/64,6),256,0,stream>>>(d, vfb, WT, cbam, cbbmm, cbu1,
                                                   asw, score, projb, pu1a);
        k_attn<<<dim3(B_,K_),256,0,stream>>>(score, cDm, vfb, tbuf, sumattn);
        k_m12<<<dim3(B_,K_),256,0,stream>>>(d, tbuf, sumattn, cWm, cbm, cWm2s, mtsp);
        k_sftail<<<B_,256,0,stream>>>(d, mtsp, cbm2s, ssf, cWzs1, cbzs1,
                                      cWzs2, cbzs2, sf);
        k_nei<<<M_,256,0,stream>>>(d, anb, bnb, cNbm, cBond, cWu2, cbu2, projb, neib);
        k_mainself<<<M_/64,256,0,stream>>>(d, neib, WT, pu1a, msb);
        k_update<<<M_/64,256,0,stream>>>(d, msb, WT, cbzm1, stm2p, s2m, vfb);
    }
    k_out<<<(M_*H_+B_*H_+255)/256,256,0,stream>>>(vfb, sf, d_out, flag);
}

// Round 10
// 760.538 us; speedup vs baseline: 1.1161x; 1.1161x over previous
//
#include <hip/hip_runtime.h>
#include <hip/hip_bf16.h>

#define B_ 32
#define N_ 512
#define NB_ 10
#define E_ 1024
#define H_ 256
#define A_ 82
#define K_ 4
#define D_ 3
#define M_ (B_*N_)   // 16384 rows

typedef unsigned short u16;
typedef __attribute__((ext_vector_type(8))) short bf16x8;
typedef __attribute__((ext_vector_type(4))) float f32x4;

__device__ __forceinline__ float b2f(u16 u){
    unsigned int x = ((unsigned int)u) << 16;
    return __builtin_bit_cast(float, x);
}
__device__ __forceinline__ u16 f2b(float f){
    unsigned int x = __builtin_bit_cast(unsigned int, f);
    unsigned int lsb = (x >> 16) & 1u;
    x += 0x7fffu + lsb;
    return (u16)(x >> 16);
}
__device__ __forceinline__ float sigmoidf_(float x){ return 1.f/(1.f+expf(-x)); }

// ---- conversion table: 31 float tensors (atom excluded; ints excluded) ----
static constexpr int CVT_N[31] = {
    B_*E_*6, B_*N_*NB_, B_*N_,
    A_*H_, H_,
    D_*K_*H_*H_, D_*K_*H_, D_*K_*H_*H_, D_*K_*H_,
    D_*K_*H_*H_, D_*K_*H_, D_*K_*H_, D_*K_,
    D_*K_*H_*H_, D_*H_, D_*H_*H_, D_*H_,
    D_*H_*H_, D_*H_, D_*H_*H_, D_*H_,
    D_*H_*H_, D_*H_, D_*H_*H_, D_*H_,
    D_*H_*H_, D_*H_, D_*(H_+6)*H_, D_*H_,
    D_*2*H_*H_, D_*H_
};
struct Offs { long v[32]; };
static constexpr Offs mk_offs(){
    Offs o{}; o.v[0]=0;
    for(int i=0;i<31;i++) o.v[i+1]=o.v[i]+CVT_N[i];
    return o;
}
static constexpr Offs CVT_OFF = mk_offs();

struct Ptrs { const void* p[31]; };

// ---------------- dtype detection: bf16 vs f32 ----------------
__global__ void k_detect(const unsigned short* __restrict__ wv_raw, int* __restrict__ flag){
    float v = b2f(wv_raw[threadIdx.x]);
    bool plaus = (v==v) && (fabsf(v) < 100.0f);
    unsigned long long m = __ballot(plaus);
    if (threadIdx.x==0) *flag = (m == ~0ULL) ? 1 : 0;
}

// ---------------- convert float inputs to fp32 workspace ----------------
__global__ void k_cvt(Ptrs ptrs, float* __restrict__ dst, const int* __restrict__ flag){
    int t = blockIdx.y;
    int n = CVT_N[t];
    int i4 = blockIdx.x*256 + threadIdx.x;
    if (i4*4 >= n) return;
    const void* src = ptrs.p[t];
    float4 o;
    if (*flag){
        ushort4 u = ((const ushort4*)src)[i4];
        o.x=b2f(u.x); o.y=b2f(u.y); o.z=b2f(u.z); o.w=b2f(u.w);
    } else {
        o = ((const float4*)src)[i4];
    }
    *(float4*)(dst + CVT_OFF.v[t] + (size_t)i4*4) = o;
}

// ======== WT precompute: 24 H×H matrices -> bf16, tiled [mi][k0/32][n][32] ========
__global__ void k_wt(const float* __restrict__ Wam, const float* __restrict__ Wu2,
                     const float* __restrict__ Wu1, const float* __restrict__ Wzm1,
                     u16* __restrict__ WT){
    int mi = blockIdx.z;
    const float* src;
    if (mi<12)      src = Wam  + (size_t)mi*H_*H_;
    else if (mi<15) src = Wu2  + (size_t)(mi-12)*(H_+6)*H_;
    else if (mi<18) src = Wu1  + (size_t)(mi-15)*2*H_*H_;
    else if (mi<21) src = Wu1  + (size_t)(mi-18)*2*H_*H_ + (size_t)H_*H_;
    else            src = Wzm1 + (size_t)(mi-21)*H_*H_;
    __shared__ float t[32][33];
    int x = threadIdx.x, y = threadIdx.y;
    int k0 = blockIdx.y*32, n0 = blockIdx.x*32;
    for(int yy=y; yy<32; yy+=8) t[yy][x] = src[(size_t)(k0+yy)*H_ + n0+x];
    __syncthreads();
    u16* dst = WT + ((size_t)mi*8 + (k0>>5))*(256*32);
    for(int yy=y; yy<32; yy+=8) dst[(size_t)(n0+yy)*32 + x] = f2b(t[x][yy]);
}

// ---------------- vertex embedding: 8 rows per block, bf16 out ----------------
__global__ void k_embed(const u16* __restrict__ atom, const float* __restrict__ Wv,
                        const float* __restrict__ bv, u16* __restrict__ vfb,
                        const int* __restrict__ flag){
    __shared__ float arow[8][A_];
    int r0 = blockIdx.x*8; int j = threadIdx.x;
    int fl = *flag;
    for(int i=j;i<8*A_;i+=256){
        int r=i/A_, a=i-r*A_;
        arow[r][a] = fl ? b2f(atom[(size_t)(r0+r)*A_+a])
                        : ((const float*)atom)[(size_t)(r0+r)*A_+a];
    }
    __syncthreads();
    float acc[8];
    float bj = bv[j];
    #pragma unroll
    for(int r=0;r<8;r++) acc[r]=bj;
    for(int a=0;a<A_;a++){
        float w = Wv[a*H_+j];
        #pragma unroll
        for(int r=0;r<8;r++) acc[r] += arow[r][a]*w;
    }
    #pragma unroll
    for(int r=0;r<8;r++){
        float v = acc[r];
        vfb[(size_t)(r0+r)*H_+j] = f2b(v>0.f ? v : 0.01f*v);
    }
}

// ---------------- sf0 ----------------
__global__ void k_sf0(const u16* __restrict__ vfb, const float* __restrict__ dmask,
                      float* __restrict__ sf){
    int b = blockIdx.x, h = threadIdx.x;
    __shared__ float mk[N_];
    for(int n=threadIdx.x;n<N_;n+=256) mk[n] = dmask[b*N_+n];
    __syncthreads();
    float s=0.f;
    #pragma unroll 8
    for(int n=0;n<N_;n++) s += mk[n]*b2f(vfb[((size_t)b*N_+n)*H_ + h]);
    sf[b*H_+h]=s;
}

// ======== S1: batched GEMV from sf: asw(k=0..3), s2m(m=4), ssf(m=5) ========
__global__ void k_s1(int d, const float* __restrict__ sf,
    const float* __restrict__ Was, const float* __restrict__ bas,
    const float* __restrict__ Wbmm,
    const float* __restrict__ Ws2m, const float* __restrict__ bs2m,
    const float* __restrict__ Wsup, const float* __restrict__ bsup,
    float* __restrict__ asw, float* __restrict__ s2m, float* __restrict__ ssf)
{
    int b = blockIdx.x, m = blockIdx.y, j = threadIdx.x;
    __shared__ float sfl[H_];
    sfl[j] = sf[b*H_+j];
    __syncthreads();
    const float* W; float bias;
    if (m < 4){ W = Was + (size_t)(d*K_+m)*H_*H_; bias = bas[(d*K_+m)*H_+j]; }
    else if (m==4){ W = Ws2m + (size_t)d*H_*H_; bias = bs2m[d*H_+j]; }
    else { W = Wsup + (size_t)d*H_*H_; bias = bsup[d*H_+j]; }
    float acc = bias;
    #pragma unroll 8
    for(int h=0;h<H_;h++) acc += sfl[h]*W[h*H_+j];
    float v = tanhf(acc);
    if (m < 4) asw[(b*K_+m)*H_+j] = v * Wbmm[(d*K_+m)*H_+j];
    else if (m==4) s2m[b*H_+j] = v;
    else ssf[b*H_+j] = v;
}

// ======== S2: stm2 partials (h-split by 4): stm2p[c][b][j] ========
__global__ void k_s2(int d, const float* __restrict__ s2m,
    const float* __restrict__ Wzm2, const float* __restrict__ bzm2,
    float* __restrict__ stm2p)
{
    int b=blockIdx.x, c=blockIdx.y, j=threadIdx.x;
    __shared__ float xl[64];
    if (j<64) xl[j] = s2m[b*H_ + c*64 + j];
    __syncthreads();
    const float* W = Wzm2 + (size_t)d*H_*H_ + (size_t)(c*64)*H_;
    float acc = (c==0) ? bzm2[d*H_+j] : 0.f;
    #pragma unroll 8
    for(int h=0;h<64;h++) acc += xl[h]*W[h*H_+j];
    stm2p[((size_t)c*B_+b)*H_+j] = acc;
}

// ================= MFMA core (R8, proven): A bf16 global, W staged from tiled WT =================
__device__ __forceinline__ void mfma_core_bt(const u16* __restrict__ A,
    const u16* __restrict__ WTg, f32x4 acc[2][8],
    u16* __restrict__ Als, u16* __restrict__ Ws)
{
    const int LSA = 40, LSW = 40;
    int tid = threadIdx.x;
    int lane = tid & 63, wave = tid >> 6;
    int wy = wave >> 1, wx = wave & 1;
    int quad = lane >> 4, l15 = lane & 15;
    #pragma unroll
    for(int mt=0;mt<2;mt++)
        #pragma unroll
        for(int nt=0;nt<8;nt++) acc[mt][nt] = (f32x4){0.f,0.f,0.f,0.f};
    int arow = tid >> 2;
    int ak8  = (tid & 3) * 8;
    for(int k0=0;k0<H_;k0+=32){
        *(bf16x8*)(Als + arow*LSA + ak8) =
            *(const bf16x8*)(A + (size_t)arow*H_ + k0 + ak8);
        const u16* wsrc = WTg + (size_t)(k0>>5)*(256*32) + tid*32;
        #pragma unroll
        for(int c=0;c<4;c++)
            *(bf16x8*)(Ws + tid*LSW + c*8) = *(const bf16x8*)(wsrc + c*8);
        __syncthreads();
        bf16x8 af[2], bfr[8];
        #pragma unroll
        for(int mt=0;mt<2;mt++)
            af[mt] = *(const bf16x8*)(Als + (wy*32+mt*16+l15)*LSA + quad*8);
        #pragma unroll
        for(int nt=0;nt<8;nt++)
            bfr[nt] = *(const bf16x8*)(Ws + (wx*128+nt*16+l15)*LSW + quad*8);
        #pragma unroll
        for(int mt=0;mt<2;mt++)
            #pragma unroll
            for(int nt=0;nt<8;nt++)
                acc[mt][nt] = __builtin_amdgcn_mfma_f32_16x16x32_bf16(
                    af[mt], bfr[nt], acc[mt][nt], 0,0,0);
        __syncthreads();
    }
}

// ================= big GEMM over vfb (R8, proven) =================
__global__ __launch_bounds__(256) void k_gemm_big(int d, const u16* __restrict__ vfb,
    const u16* __restrict__ WT, const float* __restrict__ ba_main,
    const float* __restrict__ bbmm, const float* __restrict__ bu1,
    const float* __restrict__ asw, float* __restrict__ score,
    u16* __restrict__ projb, float* __restrict__ pu1a)
{
    __shared__ u16 Als[64*40];
    __shared__ u16 Ws[256*40];
    __shared__ float sred[64][33];
    int m0 = blockIdx.x*64;
    int seg = blockIdx.y;
    int b = m0 >> 9;
    int mi;
    if (seg < 4)      mi = d*4+seg;
    else if (seg==4)  mi = 12+d;
    else              mi = 15+d;
    f32x4 acc[2][8];
    mfma_core_bt(vfb + (size_t)m0*H_, WT + (size_t)mi*H_*H_, acc, Als, Ws);
    int tid=threadIdx.x, lane=tid&63, wave=tid>>6;
    int wy=wave>>1, wx=wave&1, quad=lane>>4, l15=lane&15;
    if (seg < 4){
        const float* aswp = asw + (size_t)(b*K_+seg)*H_;
        const float* bap  = ba_main + (size_t)(d*K_+seg)*H_;
        float bbv[8], awv[8];
        #pragma unroll
        for(int nt=0;nt<8;nt++){
            int col = wx*128+nt*16+l15;
            bbv[nt]=bap[col]; awv[nt]=aswp[col];
        }
        #pragma unroll
        for(int mt=0;mt<2;mt++)
            #pragma unroll
            for(int r=0;r<4;r++){
                float p=0.f;
                #pragma unroll
                for(int nt=0;nt<8;nt++)
                    p += tanhf(acc[mt][nt][r]+bbv[nt])*awv[nt];
                int row = wy*32+mt*16+quad*4+r;
                sred[row][wx*16+l15] = p;
            }
        __syncthreads();
        if (tid < 64){
            float s=0.f;
            #pragma unroll 8
            for(int i=0;i<32;i++) s += sred[tid][i];
            score[(size_t)(b*K_+seg)*N_ + (m0&511) + tid] = s + bbmm[d*K_+seg];
        }
    } else if (seg==4){
        #pragma unroll
        for(int mt=0;mt<2;mt++)
            #pragma unroll
            for(int nt=0;nt<8;nt++){
                int col = wx*128+nt*16+l15;
                #pragma unroll
                for(int r=0;r<4;r++){
                    int row = m0 + wy*32+mt*16+quad*4+r;
                    projb[(size_t)row*H_+col] = f2b(acc[mt][nt][r]);
                }
            }
    } else {
        const float* bp = bu1 + d*H_;
        #pragma unroll
        for(int mt=0;mt<2;mt++)
            #pragma unroll
            for(int nt=0;nt<8;nt++){
                int col = wx*128+nt*16+l15;
                float bb = bp[col];
                #pragma unroll
                for(int r=0;r<4;r++){
                    int row = m0 + wy*32+mt*16+quad*4+r;
                    pu1a[(size_t)row*H_+col] = acc[mt][nt][r] + bb;
                }
            }
    }
}

// ======== fused WLN: nei (gather into LDS) -> GEMM1(+pu1a,lrelu) -> GEMM2 -> GRU ========
#define LSA2_ 264
__global__ __launch_bounds__(256) void k_wln(int d,
    const int* __restrict__ anb, const int* __restrict__ bnb,
    const float* __restrict__ nbm, const float* __restrict__ bond,
    const float* __restrict__ Wu2, const float* __restrict__ bu2,
    const u16* __restrict__ projb, const float* __restrict__ pu1a,
    const u16* __restrict__ WT, const float* __restrict__ bzm1,
    const float* __restrict__ stm2p, const float* __restrict__ s2m,
    u16* __restrict__ vfb)
{
    __shared__ u16 Als[64*LSA2_];          // 33.8 KB: nei tile, then Ms tile
    __shared__ float W2s[6][256];          // 6 KB
    __shared__ int   ai[64*NB_];           // 2.5 KB
    __shared__ float mk[64*NB_];           // 2.5 KB
    __shared__ float bfeat[64*NB_][6];     // 15.4 KB
    int m0 = blockIdx.x*64; int b = m0>>9;
    int tid = threadIdx.x;
    // stage W2 cols + indices
    {
        const float* W2 = Wu2 + (size_t)d*(H_+6)*H_ + (size_t)H_*H_;
        for(int i=tid;i<6*H_;i+=256) W2s[i>>8][i&255] = W2[i];
    }
    __shared__ int bi[64*NB_];
    for(int i=tid;i<64*NB_;i+=256){
        ai[i]=anb[(size_t)m0*NB_+i]; bi[i]=bnb[(size_t)m0*NB_+i]; mk[i]=nbm[(size_t)m0*NB_+i];
    }
    __syncthreads();
    for(int l=tid;l<64*NB_*6;l+=256){
        int e=l/6, i=l-e*6;
        bfeat[e][i] = bond[((size_t)b*E_+bi[e])*6+i];
    }
    __syncthreads();
    // nei phase: thread = column h, loop 64 rows
    {
        int h = tid;
        float bu = bu2[d*H_+h];
        for(int r=0;r<64;r++){
            float acc=0.f;
            #pragma unroll
            for(int jn=0;jn<NB_;jn++){
                int e=r*NB_+jn;
                float v = b2f(projb[((size_t)b*N_+ai[e])*H_+h]) + bu;
                #pragma unroll
                for(int i=0;i<6;i++) v += bfeat[e][i]*W2s[i][h];
                v = v>0.f? v : 0.1f*v;
                acc += mk[e]*v;
            }
            Als[r*LSA2_+h]=f2b(acc);
        }
    }
    __syncthreads();
    int lane=tid&63, wave=tid>>6, wy=wave>>1, wx=wave&1, quad=lane>>4, l15=lane&15;
    f32x4 acc[2][8];
    // GEMM1: nei @ Wu1[H:]  (A resident in Als, B direct from WT tiled)
    {
        const u16* WTg = WT + (size_t)(18+d)*H_*H_;
        #pragma unroll
        for(int mt=0;mt<2;mt++)
            #pragma unroll
            for(int nt=0;nt<8;nt++) acc[mt][nt] = (f32x4){0.f,0.f,0.f,0.f};
        #pragma unroll
        for(int k0=0;k0<H_;k0+=32){
            bf16x8 af[2], bfr[8];
            #pragma unroll
            for(int mt=0;mt<2;mt++)
                af[mt] = *(const bf16x8*)(Als + (wy*32+mt*16+l15)*LSA2_ + k0 + quad*8);
            const u16* wsrc = WTg + (size_t)(k0>>5)*(256*32);
            #pragma unroll
            for(int nt=0;nt<8;nt++)
                bfr[nt] = *(const bf16x8*)(wsrc + (wx*128+nt*16+l15)*32 + quad*8);
            #pragma unroll
            for(int mt=0;mt<2;mt++)
                #pragma unroll
                for(int nt=0;nt<8;nt++)
                    acc[mt][nt] = __builtin_amdgcn_mfma_f32_16x16x32_bf16(
                        af[mt], bfr[nt], acc[mt][nt], 0,0,0);
        }
    }
    __syncthreads();   // all GEMM1 reads of Als complete
    // Ms = lrelu(acc + pu1a) -> Als (C-layout positions == full 64x256 coverage)
    #pragma unroll
    for(int mt=0;mt<2;mt++)
        #pragma unroll
        for(int nt=0;nt<8;nt++){
            int col = wx*128+nt*16+l15;
            #pragma unroll
            for(int r=0;r<4;r++){
                int row = wy*32+mt*16+quad*4+r;
                float v = acc[mt][nt][r] + pu1a[(size_t)(m0+row)*H_+col];
                v = v>0.f? v : 0.1f*v;
                Als[row*LSA2_+col] = f2b(v);
            }
        }
    __syncthreads();
    // GEMM2: Ms @ Wzm1
    {
        const u16* WTg = WT + (size_t)(21+d)*H_*H_;
        #pragma unroll
        for(int mt=0;mt<2;mt++)
            #pragma unroll
            for(int nt=0;nt<8;nt++) acc[mt][nt] = (f32x4){0.f,0.f,0.f,0.f};
        #pragma unroll
        for(int k0=0;k0<H_;k0+=32){
            bf16x8 af[2], bfr[8];
            #pragma unroll
            for(int mt=0;mt<2;mt++)
                af[mt] = *(const bf16x8*)(Als + (wy*32+mt*16+l15)*LSA2_ + k0 + quad*8);
            const u16* wsrc = WTg + (size_t)(k0>>5)*(256*32);
            #pragma unroll
            for(int nt=0;nt<8;nt++)
                bfr[nt] = *(const bf16x8*)(wsrc + (wx*128+nt*16+l15)*32 + quad*8);
            #pragma unroll
            for(int mt=0;mt<2;mt++)
                #pragma unroll
                for(int nt=0;nt<8;nt++)
                    acc[mt][nt] = __builtin_amdgcn_mfma_f32_16x16x32_bf16(
                        af[mt], bfr[nt], acc[mt][nt], 0,0,0);
        }
    }
    // GRU epilogue
    #pragma unroll
    for(int mt=0;mt<2;mt++)
        #pragma unroll
        for(int nt=0;nt<8;nt++){
            int col = wx*128+nt*16+l15;
            float bz = bzm1[d*H_+col];
            float st = stm2p[(size_t)(0*B_+b)*H_+col] + stm2p[(size_t)(1*B_+b)*H_+col]
                     + stm2p[(size_t)(2*B_+b)*H_+col] + stm2p[(size_t)(3*B_+b)*H_+col];
            float sm = s2m[b*H_+col];
            #pragma unroll
            for(int r=0;r<4;r++){
                int row = wy*32+mt*16+quad*4+r;
                float z = sigmoidf_(acc[mt][nt][r] + bz + st);
                float ms = b2f(Als[row*LSA2_+col]);
                vfb[(size_t)(m0+row)*H_+col] = f2b((1.f-z)*ms + z*sm);
            }
        }
}

// ---------------- masked softmax (R8) ----------------
__global__ void k_softmax(float* __restrict__ score, const float* __restrict__ dmask,
                          float* __restrict__ sumattn){
    int b = blockIdx.x, k = blockIdx.y;
    int tid = threadIdx.x;
    __shared__ float sh[256];
    float* a = score + (size_t)(b*K_+k)*N_;
    float v0 = a[tid], v1 = a[tid+256];
    sh[tid]=fmaxf(v0,v1); __syncthreads();
    for(int s=128;s>0;s>>=1){ if(tid<s) sh[tid]=fmaxf(sh[tid],sh[tid+s]); __syncthreads(); }
    float m = sh[0]; __syncthreads();
    float e0 = expf(v0-m)*dmask[b*N_+tid], e1 = expf(v1-m)*dmask[b*N_+tid+256];
    sh[tid]=e0+e1; __syncthreads();
    for(int s=128;s>0;s>>=1){ if(tid<s) sh[tid]+=sh[tid+s]; __syncthreads(); }
    float S = sh[0];
    float inv = 1.f/(S+1e-6f);
    a[tid]=e0*inv; a[tid+256]=e1*inv;
    if(tid==0) sumattn[b*K_+k]=S*inv;
}

// ======== t partials (R8) ========
__global__ void k_t2(const float* __restrict__ attn, const u16* __restrict__ vfb,
                     float* __restrict__ tpart){
    int b=blockIdx.x, k=blockIdx.y, c=blockIdx.z, h=threadIdx.x;
    __shared__ float at[256];
    at[h] = attn[(size_t)(b*K_+k)*N_ + c*256 + h];
    __syncthreads();
    float acc=0.f;
    const u16* vfp = vfb + ((size_t)b*N_ + c*256)*H_ + h;
    #pragma unroll 8
    for(int n=0;n<256;n++) acc += at[n]*b2f(vfp[(size_t)n*H_]);
    tpart[((size_t)(c*B_+b)*K_+k)*H_+h]=acc;
}

// ======== fused M1+M2: t-sum -> m2s (LDS) -> mtsp[k][b][j] ========
__global__ void k_m12(int d, const float* __restrict__ tpart, const float* __restrict__ sumattn,
    const float* __restrict__ Wm, const float* __restrict__ bm,
    const float* __restrict__ Wm2s, float* __restrict__ mtsp)
{
    int b=blockIdx.x, k=blockIdx.y, j=threadIdx.x;
    __shared__ float tl[H_];
    __shared__ float m2sl[H_];
    tl[j] = tpart[((size_t)(0*B_+b)*K_+k)*H_+j] + tpart[((size_t)(1*B_+b)*K_+k)*H_+j];
    __syncthreads();
    {
        const float* W = Wm + (size_t)(d*K_+k)*H_*H_;
        float acc = sumattn[b*K_+k]*bm[(d*K_+k)*H_+j];
        #pragma unroll 8
        for(int h=0;h<H_;h++) acc += tl[h]*W[h*H_+j];
        m2sl[j]=acc;
    }
    __syncthreads();
    {
        const float* W = Wm2s + (size_t)d*(K_*H_)*H_ + (size_t)(k*H_)*H_;
        float acc=0.f;
        #pragma unroll 8
        for(int h=0;h<H_;h++) acc += m2sl[h]*W[h*H_+j];
        mtsp[((size_t)k*B_+b)*H_+j]=acc;
    }
}

// ======== fused tail: mts -> z_sup -> sf update ========
__global__ void k_sftail(int d, const float* __restrict__ mtsp, const float* __restrict__ bm2s,
    const float* __restrict__ ssf,
    const float* __restrict__ Wzs1, const float* __restrict__ bzs1,
    const float* __restrict__ Wzs2, const float* __restrict__ bzs2,
    float* __restrict__ sf)
{
    int b=blockIdx.x, j=threadIdx.x;
    __shared__ float mtsl[H_];
    __shared__ float ssl[H_];
    {
        float acc = bm2s[d*H_+j];
        #pragma unroll
        for(int c=0;c<4;c++) acc += mtsp[((size_t)c*B_+b)*H_+j];
        mtsl[j]=tanhf(acc);
        ssl[j]=ssf[b*H_+j];
    }
    __syncthreads();
    const float* W1 = Wzs1 + (size_t)d*H_*H_;
    const float* W2 = Wzs2 + (size_t)d*H_*H_;
    float acc = bzs1[d*H_+j] + bzs2[d*H_+j];
    #pragma unroll 4
    for(int h=0;h<H_;h++) acc += ssl[h]*W1[h*H_+j] + mtsl[h]*W2[h*H_+j];
    float z = sigmoidf_(acc);
    sf[b*H_+j]=(1.f-z)*ssl[j]+z*mtsl[j];
}

// ---------------- final output ----------------
__global__ void k_out(const u16* __restrict__ vfb, const float* __restrict__ sf,
                      void* __restrict__ out, const int* __restrict__ flag){
    int idx = blockIdx.x*256 + threadIdx.x;
    const int total = M_*H_ + B_*H_;
    if (idx >= total) return;
    if (*flag){
        ((u16*)out)[idx] = (idx < M_*H_) ? vfb[idx] : f2b(sf[idx - M_*H_]);
    } else {
        ((float*)out)[idx] = (idx < M_*H_) ? b2f(vfb[idx]) : sf[idx - M_*H_];
    }
}

extern "C" void kernel_launch(void* const* d_in, const int* in_sizes, int n_in,
                              void* d_out, int out_size, void* d_ws, size_t ws_size,
                              hipStream_t stream)
{
    const int* anb = (const int*)d_in[2];
    const int* bnb = (const int*)d_in[3];

    float* ws   = (float*)d_ws;
    int*   flag = (int*)ws;                 // 256 B reserved
    float* cvt  = ws + 64;
    float* p    = cvt + ((CVT_OFF.v[31] + 63) & ~63L);
    float* pu1a      = p; p += (size_t)M_*H_;
    float* sf        = p; p += B_*H_;
    float* score     = p; p += B_*K_*N_;
    float* sumattn   = p; p += 128;
    float* asw       = p; p += B_*K_*H_;
    float* s2m       = p; p += B_*H_;
    float* ssf       = p; p += B_*H_;
    float* stm2p     = p; p += 4*B_*H_;
    float* tpart     = p; p += 2*B_*K_*H_;
    float* mtsp      = p; p += 4*B_*H_;
    u16*   WT        = (u16*)p;                 // 24*H*H bf16 = 3.1 MB
    u16*   vfb       = WT  + (size_t)24*H_*H_;
    u16*   projb     = vfb + (size_t)M_*H_;

    const float* cBond = cvt + CVT_OFF.v[0];
    const float* cNbm  = cvt + CVT_OFF.v[1];
    const float* cDm   = cvt + CVT_OFF.v[2];
    const float* cWv   = cvt + CVT_OFF.v[3];
    const float* cbv   = cvt + CVT_OFF.v[4];
    const float* cWam  = cvt + CVT_OFF.v[5];
    const float* cbam  = cvt + CVT_OFF.v[6];
    const float* cWas  = cvt + CVT_OFF.v[7];
    const float* cbas  = cvt + CVT_OFF.v[8];
    const float* cWm   = cvt + CVT_OFF.v[9];
    const float* cbm   = cvt + CVT_OFF.v[10];
    const float* cWbmm = cvt + CVT_OFF.v[11];
    const float* cbbmm = cvt + CVT_OFF.v[12];
    const float* cWm2s = cvt + CVT_OFF.v[13];
    const float* cbm2s = cvt + CVT_OFF.v[14];
    const float* cWs2m = cvt + CVT_OFF.v[15];
    const float* cbs2m = cvt + CVT_OFF.v[16];
    const float* cWsup = cvt + CVT_OFF.v[17];
    const float* cbsup = cvt + CVT_OFF.v[18];
    const float* cWzm1 = cvt + CVT_OFF.v[19];
    const float* cbzm1 = cvt + CVT_OFF.v[20];
    const float* cWzm2 = cvt + CVT_OFF.v[21];
    const float* cbzm2 = cvt + CVT_OFF.v[22];
    const float* cWzs1 = cvt + CVT_OFF.v[23];
    const float* cbzs1 = cvt + CVT_OFF.v[24];
    const float* cWzs2 = cvt + CVT_OFF.v[25];
    const float* cbzs2 = cvt + CVT_OFF.v[26];
    const float* cWu2  = cvt + CVT_OFF.v[27];
    const float* cbu2  = cvt + CVT_OFF.v[28];
    const float* cWu1  = cvt + CVT_OFF.v[29];
    const float* cbu1  = cvt + CVT_OFF.v[30];

    Ptrs ptrs;
    {
        int idx[31] = {1,4,5,6,7,8,9,10,11,12,13,14,15,16,17,18,19,20,21,
                       22,23,24,25,26,27,28,29,30,31,32,33};
        for(int i=0;i<31;i++) ptrs.p[i] = d_in[idx[i]];
    }

    k_detect<<<1,64,0,stream>>>((const unsigned short*)d_in[6], flag);
    {
        int maxv4 = (D_*K_*H_*H_ + 3)/4;
        int gx = (maxv4 + 255)/256;
        k_cvt<<<dim3(gx,31),256,0,stream>>>(ptrs, cvt, flag);
    }
    k_wt<<<dim3(8,8,24),dim3(32,8),0,stream>>>(cWam, cWu2, cWu1, cWzm1, WT);

    k_embed<<<M_/8,256,0,stream>>>((const u16*)d_in[0], cWv, cbv, vfb, flag);
    k_sf0<<<B_,256,0,stream>>>(vfb, cDm, sf);
    for(int d=0; d<D_; d++){
        k_s1<<<dim3(B_,6),256,0,stream>>>(d, sf, cWas, cbas, cWbmm,
                                          cWs2m, cbs2m, cWsup, cbsup, asw, s2m, ssf);
        k_s2<<<dim3(B_,4),256,0,stream>>>(d, s2m, cWzm2, cbzm2, stm2p);
        k_gemm_big<<<dim3(M_/64,6),256,0,stream>>>(d, vfb, WT, cbam, cbbmm, cbu1,
                                                   asw, score, projb, pu1a);
        k_softmax<<<dim3(B_,K_),256,0,stream>>>(score, cDm, sumattn);
        k_t2<<<dim3(B_,K_,2),256,0,stream>>>(score, vfb, tpart);
        k_m12<<<dim3(B_,K_),256,0,stream>>>(d, tpart, sumattn, cWm, cbm, cWm2s, mtsp);
        k_sftail<<<B_,256,0,stream>>>(d, mtsp, cbm2s, ssf, cWzs1, cbzs1,
                                      cWzs2, cbzs2, sf);
        k_wln<<<M_/64,256,0,stream>>>(d, anb, bnb, cNbm, cBond, cWu2, cbu2,
                                      projb, pu1a, WT, cbzm1, stm2p, s2m, vfb);
    }
    k_out<<<(M_*H_+B_*H_+255)/256,256,0,stream>>>(vfb, sf, d_out, flag);
}